// Round 5
// baseline (718.504 us; speedup 1.0000x reference)
//
#include <hip/hip_runtime.h>
#include <stdint.h>

#define BN   1024
#define FEATN 512
#define HDIM 256
#define TAUF 5.0f
#define EPSF 1e-8f

typedef __attribute__((ext_vector_type(8))) short short8;
typedef __attribute__((ext_vector_type(4))) float f32x4;

// float -> bf16, round-to-nearest-even, returned as raw short (prep only)
__device__ __forceinline__ short f2bf(float f) {
  union { float f; unsigned u; } c; c.f = f;
  return (short)((c.u + 0x7fffu + ((c.u >> 16) & 1u)) >> 16);
}

#if defined(__has_builtin)
#if __has_builtin(__builtin_amdgcn_cvt_pk_bf16_f32)
#define HAVE_CVT_PK_BF16 1
#endif
#if __has_builtin(__builtin_amdgcn_rcpf)
#define HAVE_RCPF 1
#endif
#endif

#ifdef HAVE_RCPF
__device__ __forceinline__ float fast_rcp(float x) { return __builtin_amdgcn_rcpf(x); }
#else
__device__ __forceinline__ float fast_rcp(float x) { return 1.0f / x; }
#endif

// pack bf16(a) low16, bf16(b) high16 (RTNE)
#ifdef HAVE_CVT_PK_BF16
typedef __attribute__((ext_vector_type(2))) __bf16 bf16x2;
__device__ __forceinline__ int cvt2(float a, float b) {
  bf16x2 r = __builtin_amdgcn_cvt_pk_bf16_f32(a, b);
  int i; __builtin_memcpy(&i, &r, 4); return i;
}
#else
__device__ __forceinline__ int cvt2(float a, float b) {
  unsigned ua = __float_as_uint(a), ub = __float_as_uint(b);
  ua = ua + 0x7fffu + ((ua >> 16) & 1u);
  ub = ub + 0x7fffu + ((ub >> 16) & 1u);
  return (int)__builtin_amdgcn_perm(ub, ua, 0x07060302u);
}
#endif

// tanh-approx gelu == x * sigmoid(1.5957691x + 0.0713548x^3)
__device__ __forceinline__ float gelu_fast(float x) {
  float s = fmaf(x * x, 0.07135481627f, 1.59576912161f) * x;
  float e = __expf(s);
  return x * e * fast_rcp(e + 1.0f);
}

// ---------------- prep: swizzle W1[:512] to bf16 frag order; label softmax ----------------
__global__ __launch_bounds__(256) void prep_kernel(const float* __restrict__ W1,
                                                   const float* __restrict__ lg,
                                                   short* __restrict__ w1swz,
                                                   float* __restrict__ oh) {
  int b = blockIdx.x, t = threadIdx.x;
  if (b < FEATN) {
    int k = b, n = t;
    // B-frag layout: element (k,n) at ((k>>3)*256 + n)*8 + (k&7)
    w1swz[(((k >> 3) * HDIM) + n) * 8 + (k & 7)] = f2bf(W1[k * HDIM + n]);
  } else {
    int i = (b - FEATN) * 256 + t;
    float l0 = lg[2 * i], l1 = lg[2 * i + 1];
    float m = fmaxf(l0, l1);
    float e0 = __expf(l0 - m), e1 = __expf(l1 - m);
    float inv = 1.0f / (e0 + e1);
    oh[2 * i] = e0 * inv;
    oh[2 * i + 1] = e1 * inv;
  }
}

// ---------------- main: pair-GEMM + gelu + W2-dot partial, atomic accumulate ----------------
// Block tile: 128 pairs (16i x 8j) x 128 n (n-half = blockIdx.z). Wave = 32 pairs x 128 n,
// acc[2][8] = 64 AGPRs. NO LDS, NO barriers: X and B read via L1 (broadcast-friendly),
// immediate-offset loads. Partial scores atomicAdd'ed into part[] (zeroed by memsetAsync).
__global__ __launch_bounds__(256, 3) void gemm_kernel(const float* __restrict__ X,
                                                      const short* __restrict__ w1swz,
                                                      const float* __restrict__ oh,
                                                      const float* __restrict__ W1,
                                                      const float* __restrict__ b1,
                                                      const float* __restrict__ W2,
                                                      float* __restrict__ part) {
  const int tid = threadIdx.x;
  const int L = tid & 63;
  const int w = tid >> 6;              // wave id == m-quarter (32 pairs)
  const int i0 = blockIdx.y * 16;
  const int j0 = blockIdx.x * 8;
  const int nh = blockIdx.z;           // n-half

  const int nl = L & 15;
  const int d = nl >> 3;
  const int jj = L & 7;
  const int koct = L >> 4;

  // X pointers: per-kt access via immediate offset kt*128 bytes (<= 1920, fits 13-bit imm)
  const float* xi0 = X + (i0 + w * 4 + d) * FEATN + koct * 8;        // t=0 row
  const float* xi1 = xi0 + 2 * FEATN;                                 // t=1 row
  const float* xj  = X + (j0 + jj) * FEATN + koct * 8;
  // B base for this lane (short units); step stride 8192 shorts (16 KB)
  const short* bp = w1swz + ((koct * HDIM) + nh * 128 + nl) * 8;

  f32x4 acc[2][8];
  #pragma unroll
  for (int t = 0; t < 2; ++t)
    #pragma unroll
    for (int u = 0; u < 8; ++u) acc[t][u] = (f32x4){0.f, 0.f, 0.f, 0.f};

  #pragma unroll 2
  for (int kt = 0; kt < 16; ++kt) {
    // B fragments for this k-step (8 x 16B, imm offsets 0..1792)
    short8 bfr[8];
    #pragma unroll
    for (int u = 0; u < 8; ++u)
      bfr[u] = *(const short8*)(bp + u * 128);
    bp += 8192;

    // X slices (L1-broadcast: xi shared by 8 lanes, xj by 2)
    float4 xjA  = *(const float4*)(xj  + kt * 32);
    float4 xjB  = *(const float4*)(xj  + kt * 32 + 4);
    float4 xiA0 = *(const float4*)(xi0 + kt * 32);
    float4 xiB0 = *(const float4*)(xi0 + kt * 32 + 4);
    float4 xiA1 = *(const float4*)(xi1 + kt * 32);
    float4 xiB1 = *(const float4*)(xi1 + kt * 32 + 4);

    union { int i[4]; short8 v; } A0, A1;
    A0.i[0] = cvt2(fabsf(xiA0.x - xjA.x), fabsf(xiA0.y - xjA.y));
    A0.i[1] = cvt2(fabsf(xiA0.z - xjA.z), fabsf(xiA0.w - xjA.w));
    A0.i[2] = cvt2(fabsf(xiB0.x - xjB.x), fabsf(xiB0.y - xjB.y));
    A0.i[3] = cvt2(fabsf(xiB0.z - xjB.z), fabsf(xiB0.w - xjB.w));
    A1.i[0] = cvt2(fabsf(xiA1.x - xjA.x), fabsf(xiA1.y - xjA.y));
    A1.i[1] = cvt2(fabsf(xiA1.z - xjA.z), fabsf(xiA1.w - xjA.w));
    A1.i[2] = cvt2(fabsf(xiB1.x - xjB.x), fabsf(xiB1.y - xjB.y));
    A1.i[3] = cvt2(fabsf(xiB1.z - xjB.z), fabsf(xiB1.w - xjB.w));

    #pragma unroll
    for (int u = 0; u < 8; ++u) {
      acc[0][u] = __builtin_amdgcn_mfma_f32_16x16x32_bf16(A0.v, bfr[u], acc[0][u], 0, 0, 0);
      acc[1][u] = __builtin_amdgcn_mfma_f32_16x16x32_bf16(A1.v, bfr[u], acc[1][u], 0, 0, 0);
    }
  }

  // ---- epilogue: + label rank-2 + b1, fast gelu, dot W2 over this n-half, reduce, atomicAdd ----
  const int q = L >> 4;
  float w1l0[8], w1l1[8], bb1[8], ww2[8];
  #pragma unroll
  for (int u = 0; u < 8; ++u) {
    int n = nh * 128 + u * 16 + nl;
    w1l0[u] = W1[512 * HDIM + n];
    w1l1[u] = W1[513 * HDIM + n];
    bb1[u] = b1[n];
    ww2[u] = W2[n];
  }
  #pragma unroll
  for (int t = 0; t < 2; ++t) {
    #pragma unroll
    for (int r = 0; r < 4; ++r) {
      int p = w * 32 + t * 16 + q * 4 + r;   // C/D: row = quad*4 + reg
      int gi = i0 + (p >> 3), gj = j0 + (p & 7);
      float l0v = oh[2 * gi] * oh[2 * gj];
      float l1v = oh[2 * gi + 1] * oh[2 * gj + 1];
      float v = 0.f;
      #pragma unroll
      for (int u = 0; u < 8; ++u) {
        float e = acc[t][u][r] + l0v * w1l0[u] + l1v * w1l1[u] + bb1[u];
        v += gelu_fast(e) * ww2[u];
      }
      v += __shfl_xor(v, 1, 64);
      v += __shfl_xor(v, 2, 64);
      v += __shfl_xor(v, 4, 64);
      v += __shfl_xor(v, 8, 64);       // sum over 16 cols of the quad (x8 u = this n-half)
      if (nl == 0) atomicAdd(&part[(size_t)gi * BN + gj], v);
    }
  }
}

// ---------------- sigmoid + row softmax; writes both outputs ----------------
__global__ __launch_bounds__(256) void softmax_kernel(const float* __restrict__ adj,
                                                      float* __restrict__ hs,   // in: partial sums, out: h_scores
                                                      const float* __restrict__ b2,
                                                      float* __restrict__ out) {
  int i = blockIdx.x, t = threadIdx.x;
  __shared__ float redm[4];
  __shared__ float reds[4];
  const float b2v = b2[0];
  float l[4], hv[4];
  float mx = -1e30f;
  #pragma unroll
  for (int k = 0; k < 4; ++k) {
    int j = t + k * 256;
    float s = hs[(size_t)i * BN + j];
    float h = fast_rcp(1.0f + __expf(-(s + b2v)));
    hv[k] = h;
    float lv = adj[(size_t)i * BN + j] + TAUF * __logf(h + EPSF);
    l[k] = lv;
    mx = fmaxf(mx, lv);
  }
  #pragma unroll
  for (int o = 1; o <= 32; o <<= 1) mx = fmaxf(mx, __shfl_xor(mx, o, 64));
  if ((t & 63) == 0) redm[t >> 6] = mx;
  __syncthreads();
  mx = fmaxf(fmaxf(redm[0], redm[1]), fmaxf(redm[2], redm[3]));
  float ex[4];
  float se = 0.f;
  #pragma unroll
  for (int k = 0; k < 4; ++k) { ex[k] = __expf(l[k] - mx); se += ex[k]; }
  #pragma unroll
  for (int o = 1; o <= 32; o <<= 1) se += __shfl_xor(se, o, 64);
  if ((t & 63) == 0) reds[t >> 6] = se;
  __syncthreads();
  se = reds[0] + reds[1] + reds[2] + reds[3];
  float inv = fast_rcp(se);
  #pragma unroll
  for (int k = 0; k < 4; ++k) {
    int j = t + k * 256;
    out[(size_t)i * BN + j] = ex[k] * inv;
    hs[(size_t)i * BN + j] = hv[k];
  }
}

extern "C" void kernel_launch(void* const* d_in, const int* in_sizes, int n_in,
                              void* d_out, int out_size, void* d_ws, size_t ws_size,
                              hipStream_t stream) {
  (void)in_sizes; (void)n_in; (void)out_size; (void)ws_size;
  const float* X   = (const float*)d_in[0];
  const float* lg  = (const float*)d_in[1];
  const float* adj = (const float*)d_in[2];
  const float* W1  = (const float*)d_in[3];
  const float* b1  = (const float*)d_in[4];
  const float* W2  = (const float*)d_in[5];
  const float* b2  = (const float*)d_in[6];
  float* out = (float*)d_out;                       // [0,B^2): adj_refined, [B^2,2B^2): h_scores
  short* w1swz = (short*)d_ws;                      // 512*256 bf16 = 256 KB
  float* oh = (float*)((char*)d_ws + FEATN * HDIM * 2);  // 1024*2 f32

  float* out_hs = out + (size_t)BN * BN;

  // zero the partial-score accumulator (re-poisoned to 0xAA before every launch)
  hipMemsetAsync(out_hs, 0, (size_t)BN * BN * sizeof(float), stream);

  prep_kernel<<<dim3(FEATN + 4), dim3(256), 0, stream>>>(W1, lg, w1swz, oh);
  gemm_kernel<<<dim3(128, 64, 2), dim3(256), 0, stream>>>(X, w1swz, oh, W1, b1, W2, out_hs);
  softmax_kernel<<<dim3(BN), dim3(256), 0, stream>>>(adj, out_hs, b2, out);
}

// Round 6
// 620.735 us; speedup vs baseline: 1.1575x; 1.1575x over previous
//
#include <hip/hip_runtime.h>
#include <stdint.h>

#define BN   1024
#define FEATN 512
#define HDIM 256
#define TAUF 5.0f
#define EPSF 1e-8f

typedef __attribute__((ext_vector_type(8))) short short8;
typedef __attribute__((ext_vector_type(4))) float f32x4;

// float -> bf16, round-to-nearest-even, returned as raw short (prep only)
__device__ __forceinline__ short f2bf(float f) {
  union { float f; unsigned u; } c; c.f = f;
  return (short)((c.u + 0x7fffu + ((c.u >> 16) & 1u)) >> 16);
}

#if defined(__has_builtin)
#if __has_builtin(__builtin_amdgcn_cvt_pk_bf16_f32)
#define HAVE_CVT_PK_BF16 1
#endif
#if __has_builtin(__builtin_amdgcn_rcpf)
#define HAVE_RCPF 1
#endif
#endif

#ifdef HAVE_RCPF
__device__ __forceinline__ float fast_rcp(float x) { return __builtin_amdgcn_rcpf(x); }
#else
__device__ __forceinline__ float fast_rcp(float x) { return 1.0f / x; }
#endif

// pack bf16(a) low16, bf16(b) high16 (RTNE)
#ifdef HAVE_CVT_PK_BF16
typedef __attribute__((ext_vector_type(2))) __bf16 bf16x2;
__device__ __forceinline__ int cvt2(float a, float b) {
  bf16x2 r = __builtin_amdgcn_cvt_pk_bf16_f32(a, b);
  int i; __builtin_memcpy(&i, &r, 4); return i;
}
#else
__device__ __forceinline__ int cvt2(float a, float b) {
  unsigned ua = __float_as_uint(a), ub = __float_as_uint(b);
  ua = ua + 0x7fffu + ((ua >> 16) & 1u);
  ub = ub + 0x7fffu + ((ub >> 16) & 1u);
  return (int)__builtin_amdgcn_perm(ub, ua, 0x07060302u);
}
#endif

// tanh-approx gelu == x * sigmoid(1.5957691x + 0.0713548x^3)
__device__ __forceinline__ float gelu_fast(float x) {
  float s = fmaf(x * x, 0.07135481627f, 1.59576912161f) * x;
  float e = __expf(s);
  return x * e * fast_rcp(e + 1.0f);
}

// ---------------- prep: swizzle W1[:512] to bf16 frag order; label softmax ----------------
__global__ __launch_bounds__(256) void prep_kernel(const float* __restrict__ W1,
                                                   const float* __restrict__ lg,
                                                   short* __restrict__ w1swz,
                                                   float* __restrict__ oh) {
  int b = blockIdx.x, t = threadIdx.x;
  if (b < FEATN) {
    int k = b, n = t;
    // B-frag layout: element (k,n) at ((k>>3)*256 + n)*8 + (k&7)
    w1swz[(((k >> 3) * HDIM) + n) * 8 + (k & 7)] = f2bf(W1[k * HDIM + n]);
  } else {
    int i = (b - FEATN) * 256 + t;
    float l0 = lg[2 * i], l1 = lg[2 * i + 1];
    float m = fmaxf(l0, l1);
    float e0 = __expf(l0 - m), e1 = __expf(l1 - m);
    float inv = 1.0f / (e0 + e1);
    oh[2 * i] = e0 * inv;
    oh[2 * i + 1] = e1 * inv;
  }
}

// ---------------- main: fused pair-GEMM + gelu + W2-dot + sigmoid ----------------
// Tile: 64 pairs (8i x 8j) x 256 n. Wave w owns m-subtile w (16 pairs) across ALL 16
// n-subtiles: construct-once, no sA, no in-loop barriers. acc[16] = 64 AGPRs.
// X staged in LDS (33 KB, stride 516); B-frags coalesced from L1/L2 (shared 16 KB/step).
__global__ __launch_bounds__(256, 4) void gemm_kernel(const float* __restrict__ X,
                                                      const short* __restrict__ w1swz,
                                                      const float* __restrict__ oh,
                                                      const float* __restrict__ W1,
                                                      const float* __restrict__ b1,
                                                      const float* __restrict__ W2,
                                                      const float* __restrict__ b2,
                                                      float* __restrict__ out_hs) {
  __shared__ __align__(16) float sXi[8 * 516];
  __shared__ __align__(16) float sXj[8 * 516];

  const int tid = threadIdx.x;
  const int L = tid & 63;
  const int w = tid >> 6;              // wave id == m-subtile (16 pairs)
  const int i0 = blockIdx.y * 8;
  const int j0 = blockIdx.x * 8;

  // ---- stage 16 X rows (8 i, 8 j), 512 f32 each, LDS stride 516 ----
  #pragma unroll
  for (int it = 0; it < 8; ++it) {
    int idx = tid + it * 256;          // 2048 float4 tasks
    int row = idx >> 7;                // 0..15
    int c = idx & 127;
    int grow = (row < 8) ? (i0 + row) : (j0 + row - 8);
    float4 v = *(const float4*)(X + grow * FEATN + c * 4);
    float* dst = ((row < 8) ? (sXi + row * 516) : (sXj + (row - 8) * 516)) + c * 4;
    *(float4*)dst = v;
  }

  // ---- lane decode: pair p = w*16 + nl; ii = p>>3 = 2w + (nl>>3), jj = nl&7 ----
  const int nl = L & 15;
  const int koct = L >> 4;
  const float* cxi = sXi + (2 * w + (nl >> 3)) * 516 + koct * 8;
  const float* cxj = sXj + (nl & 7) * 516 + koct * 8;

  // B-frag per-lane base (short units): step kt at +kt*8192, n-subtile u at +u*128
  const short* bp = w1swz + ((koct * HDIM) + nl) * 8;

  f32x4 acc[16];
  #pragma unroll
  for (int u = 0; u < 16; ++u) acc[u] = (f32x4){0.f, 0.f, 0.f, 0.f};

  __syncthreads();

  #pragma unroll 1
  for (int kt = 0; kt < 16; ++kt) {
    // A-frag construct: 4 broadcast-friendly ds_read_b128 + 8 sub + 4 pack
    float4 xiA = *(const float4*)(cxi + kt * 32);
    float4 xiB = *(const float4*)(cxi + kt * 32 + 4);
    float4 xjA = *(const float4*)(cxj + kt * 32);
    float4 xjB = *(const float4*)(cxj + kt * 32 + 4);
    union { int i[4]; short8 v; } A;
    A.i[0] = cvt2(fabsf(xiA.x - xjA.x), fabsf(xiA.y - xjA.y));
    A.i[1] = cvt2(fabsf(xiA.z - xjA.z), fabsf(xiA.w - xjA.w));
    A.i[2] = cvt2(fabsf(xiB.x - xjB.x), fabsf(xiB.y - xjB.y));
    A.i[3] = cvt2(fabsf(xiB.z - xjB.z), fabsf(xiB.w - xjB.w));

    // 16 n-subtiles in batches of 4 to cap live VGPRs
    const short* bs = bp + kt * 8192;
    #pragma unroll
    for (int h = 0; h < 4; ++h) {
      short8 bfr[4];
      #pragma unroll
      for (int u = 0; u < 4; ++u)
        bfr[u] = *(const short8*)(bs + h * 512 + u * 128);
      #pragma unroll
      for (int u = 0; u < 4; ++u)
        acc[h * 4 + u] = __builtin_amdgcn_mfma_f32_16x16x32_bf16(A.v, bfr[u], acc[h * 4 + u], 0, 0, 0);
    }
  }

  // ---- epilogue: + label rank-2 + b1, fast gelu, dot W2, in-wave reduce, sigmoid ----
  const int q = L >> 4;
  float vsum[4] = {0.f, 0.f, 0.f, 0.f};
  float l0v[4], l1v[4];
  #pragma unroll
  for (int r = 0; r < 4; ++r) {
    int p = w * 16 + q * 4 + r;        // C/D: row = quad*4 + reg
    int gi = i0 + (p >> 3), gj = j0 + (p & 7);
    l0v[r] = oh[2 * gi] * oh[2 * gj];
    l1v[r] = oh[2 * gi + 1] * oh[2 * gj + 1];
  }
  #pragma unroll
  for (int u = 0; u < 16; ++u) {
    int n = u * 16 + nl;
    float a0 = W1[512 * HDIM + n];
    float a1 = W1[513 * HDIM + n];
    float bb = b1[n];
    float w2v = W2[n];
    #pragma unroll
    for (int r = 0; r < 4; ++r) {
      float e = acc[u][r] + l0v[r] * a0 + l1v[r] * a1 + bb;
      vsum[r] += gelu_fast(e) * w2v;
    }
  }
  const float b2v = b2[0];
  #pragma unroll
  for (int r = 0; r < 4; ++r) {
    float v = vsum[r];
    v += __shfl_xor(v, 1, 64);
    v += __shfl_xor(v, 2, 64);
    v += __shfl_xor(v, 4, 64);
    v += __shfl_xor(v, 8, 64);         // sum over the 16 nl lanes of this quad
    if (nl == 0) {
      int p = w * 16 + q * 4 + r;
      int gi = i0 + (p >> 3), gj = j0 + (p & 7);
      out_hs[(size_t)gi * BN + gj] = fast_rcp(1.0f + __expf(-(v + b2v)));
    }
  }
}

// ---------------- row softmax of adj + TAU*log(hs + EPS) ----------------
__global__ __launch_bounds__(256) void softmax_kernel(const float* __restrict__ adj,
                                                      const float* __restrict__ hs,
                                                      float* __restrict__ out) {
  int i = blockIdx.x, t = threadIdx.x;
  __shared__ float redm[4];
  __shared__ float reds[4];
  float l[4];
  float mx = -1e30f;
  #pragma unroll
  for (int k = 0; k < 4; ++k) {
    int j = t + k * 256;
    float lv = adj[(size_t)i * BN + j] + TAUF * __logf(hs[(size_t)i * BN + j] + EPSF);
    l[k] = lv;
    mx = fmaxf(mx, lv);
  }
  #pragma unroll
  for (int o = 1; o <= 32; o <<= 1) mx = fmaxf(mx, __shfl_xor(mx, o, 64));
  if ((t & 63) == 0) redm[t >> 6] = mx;
  __syncthreads();
  mx = fmaxf(fmaxf(redm[0], redm[1]), fmaxf(redm[2], redm[3]));
  float ex[4];
  float se = 0.f;
  #pragma unroll
  for (int k = 0; k < 4; ++k) { ex[k] = __expf(l[k] - mx); se += ex[k]; }
  #pragma unroll
  for (int o = 1; o <= 32; o <<= 1) se += __shfl_xor(se, o, 64);
  if ((t & 63) == 0) reds[t >> 6] = se;
  __syncthreads();
  se = reds[0] + reds[1] + reds[2] + reds[3];
  float inv = fast_rcp(se);
  #pragma unroll
  for (int k = 0; k < 4; ++k) out[(size_t)i * BN + t + k * 256] = ex[k] * inv;
}

extern "C" void kernel_launch(void* const* d_in, const int* in_sizes, int n_in,
                              void* d_out, int out_size, void* d_ws, size_t ws_size,
                              hipStream_t stream) {
  (void)in_sizes; (void)n_in; (void)out_size; (void)ws_size;
  const float* X   = (const float*)d_in[0];
  const float* lg  = (const float*)d_in[1];
  const float* adj = (const float*)d_in[2];
  const float* W1  = (const float*)d_in[3];
  const float* b1  = (const float*)d_in[4];
  const float* W2  = (const float*)d_in[5];
  const float* b2  = (const float*)d_in[6];
  float* out = (float*)d_out;                       // [0,B^2): adj_refined, [B^2,2B^2): h_scores
  short* w1swz = (short*)d_ws;                      // 512*256 bf16 = 256 KB
  float* oh = (float*)((char*)d_ws + FEATN * HDIM * 2);  // 1024*2 f32

  float* out_hs = out + (size_t)BN * BN;

  prep_kernel<<<dim3(FEATN + 4), dim3(256), 0, stream>>>(W1, lg, w1swz, oh);
  gemm_kernel<<<dim3(128, 128), dim3(256), 0, stream>>>(X, w1swz, oh, W1, b1, W2, b2, out_hs);
  softmax_kernel<<<dim3(BN), dim3(256), 0, stream>>>(adj, out_hs, out);
}

// Round 7
// 401.336 us; speedup vs baseline: 1.7903x; 1.5467x over previous
//
#include <hip/hip_runtime.h>
#include <stdint.h>

#define BN   1024
#define FEATN 512
#define HDIM 256
#define TAUF 5.0f
#define EPSF 1e-8f

typedef __attribute__((ext_vector_type(8))) _Float16 half8;
typedef __attribute__((ext_vector_type(4))) float f32x4;

#if defined(__has_builtin)
#if __has_builtin(__builtin_amdgcn_rcpf)
#define HAVE_RCPF 1
#endif
#endif

#ifdef HAVE_RCPF
__device__ __forceinline__ float fast_rcp(float x) { return __builtin_amdgcn_rcpf(x); }
#else
__device__ __forceinline__ float fast_rcp(float x) { return 1.0f / x; }
#endif

// tanh-approx gelu == x * sigmoid(1.5957691x + 0.0713548x^3)
__device__ __forceinline__ float gelu_fast(float x) {
  float s = fmaf(x * x, 0.07135481627f, 1.59576912161f) * x;
  float e = __expf(s);
  return x * e * fast_rcp(e + 1.0f);
}

// ---------------- prep: W1[:512] -> fp16 frag order; label softmax ----------------
__global__ __launch_bounds__(256) void prep_kernel(const float* __restrict__ W1,
                                                   const float* __restrict__ lg,
                                                   _Float16* __restrict__ w1h,
                                                   float* __restrict__ oh) {
  int b = blockIdx.x, t = threadIdx.x;
  if (b < FEATN) {
    int k = b, n = t;
    // B-frag layout: element (k,n) at ((k>>3)*256 + n)*8 + (k&7)
    w1h[(((k >> 3) * HDIM) + n) * 8 + (k & 7)] = (_Float16)W1[k * HDIM + n];
  } else {
    int i = (b - FEATN) * 256 + t;
    float l0 = lg[2 * i], l1 = lg[2 * i + 1];
    float m = fmaxf(l0, l1);
    float e0 = __expf(l0 - m), e1 = __expf(l1 - m);
    float inv = 1.0f / (e0 + e1);
    oh[2 * i] = e0 * inv;
    oh[2 * i + 1] = e1 * inv;
  }
}

// ---------------- main: fused pair-GEMM (fp16 MFMA) + gelu + W2-dot + sigmoid ----------------
// Tile: 64 pairs (8i x 8j) x 256 n. Waves split n (unique B per wave). A-frags shared via
// double-buffered sA in 2-step chunks -> ONE barrier per 2 k-steps. X staged as fp16.
__global__ __launch_bounds__(256, 4) void gemm_kernel(const float* __restrict__ X,
                                                      const _Float16* __restrict__ w1h,
                                                      const float* __restrict__ oh,
                                                      const float* __restrict__ W1,
                                                      const float* __restrict__ b1,
                                                      const float* __restrict__ W2,
                                                      const float* __restrict__ b2,
                                                      float* __restrict__ out_hs) {
  __shared__ __align__(16) _Float16 sX[16 * 520];     // rows 0-7: i, 8-15: j (stride 520 fp16)
  __shared__ __align__(16) half8 sA[2][2][4][64];     // [buf][step-in-chunk][m-subtile][lane]
  __shared__ float sScore[64 * 4];
  __shared__ float sLab0[64], sLab1[64];

  const int tid = threadIdx.x;
  const int L = tid & 63;
  const int w = tid >> 6;              // wave id == n-quarter AND construct m-subtile
  const int i0 = blockIdx.y * 8;
  const int j0 = blockIdx.x * 8;

  // ---- stage 16 X rows, f32 -> fp16 (RTNE), LDS stride 520 fp16 ----
  #pragma unroll
  for (int it = 0; it < 4; ++it) {
    int idx = tid + it * 256;          // 1024 octet tasks (16 rows x 64 octets)
    int row = idx >> 6;
    int oc = idx & 63;
    int grow = (row < 8) ? (i0 + row) : (j0 + row - 8);
    const float* gp = X + grow * FEATN + oc * 8;
    float4 a = *(const float4*)gp;
    float4 c = *(const float4*)(gp + 4);
    half8 hv;
    hv[0] = (_Float16)a.x; hv[1] = (_Float16)a.y; hv[2] = (_Float16)a.z; hv[3] = (_Float16)a.w;
    hv[4] = (_Float16)c.x; hv[5] = (_Float16)c.y; hv[6] = (_Float16)c.z; hv[7] = (_Float16)c.w;
    *(half8*)(sX + row * 520 + oc * 8) = hv;
  }
  if (tid < 64) {
    int gi = i0 + (tid >> 3), gj = j0 + (tid & 7);
    sLab0[tid] = oh[2 * gi] * oh[2 * gj];
    sLab1[tid] = oh[2 * gi + 1] * oh[2 * gj + 1];
  }

  // ---- construct decode: wave w builds m-subtile w's frag for lane L ----
  // pair m = 16w + (L&15); ii = 2w + ((L&15)>>3); jj = L&7; koct = L>>4
  const int nl = L & 15;
  const int koct = L >> 4;
  const _Float16* cxi = sX + (2 * w + (nl >> 3)) * 520 + koct * 8;
  const _Float16* cxj = sX + (8 + (L & 7)) * 520 + koct * 8;

  // B-frag per-lane base (fp16 elems): step kt at +kt*8192, n-subtile u at +u*128
  const _Float16* bbase = w1h + ((koct * HDIM) + w * 64 + nl) * 8;

  f32x4 acc[4][4];
  #pragma unroll
  for (int s = 0; s < 4; ++s)
    #pragma unroll
    for (int u = 0; u < 4; ++u) acc[s][u] = (f32x4){0.f, 0.f, 0.f, 0.f};

  __syncthreads();

  // construct one step's A-frag (fp16 pk-sub + abs mask) into sA[buf][st]
  #define CONSTRUCT(kt, buf, st)                                          \
    {                                                                     \
      half8 xi = *(const half8*)(cxi + (kt) * 32);                        \
      half8 xj = *(const half8*)(cxj + (kt) * 32);                        \
      union { half8 h; unsigned u4[4]; } U;                               \
      U.h = xi - xj;                                                      \
      U.u4[0] &= 0x7FFF7FFFu; U.u4[1] &= 0x7FFF7FFFu;                     \
      U.u4[2] &= 0x7FFF7FFFu; U.u4[3] &= 0x7FFF7FFFu;                     \
      sA[buf][st][w][L] = U.h;                                            \
    }

  #define CONSUME(kt, buf, st)                                            \
    {                                                                     \
      half8 afr[4];                                                       \
      _Pragma("unroll")                                                   \
      for (int s = 0; s < 4; ++s) afr[s] = sA[buf][st][s][L];             \
      half8 bfr[4];                                                       \
      _Pragma("unroll")                                                   \
      for (int u = 0; u < 4; ++u)                                         \
        bfr[u] = *(const half8*)(bbase + (kt) * 8192 + u * 128);          \
      _Pragma("unroll")                                                   \
      for (int s = 0; s < 4; ++s)                                         \
        _Pragma("unroll")                                                 \
        for (int u = 0; u < 4; ++u)                                       \
          acc[s][u] = __builtin_amdgcn_mfma_f32_16x16x32_f16(             \
              afr[s], bfr[u], acc[s][u], 0, 0, 0);                        \
    }

  // prologue: chunk 0 (steps 0,1)
  CONSTRUCT(0, 0, 0)
  CONSTRUCT(1, 0, 1)
  __syncthreads();

  #pragma unroll 2
  for (int t = 0; t < 8; ++t) {
    const int buf = t & 1;
    CONSUME(2 * t, buf, 0)
    CONSUME(2 * t + 1, buf, 1)
    if (t < 7) {
      CONSTRUCT(2 * t + 2, 1 - buf, 0)
      CONSTRUCT(2 * t + 3, 1 - buf, 1)
    }
    __syncthreads();
  }
  #undef CONSTRUCT
  #undef CONSUME

  // ---- epilogue: + label rank-2 + b1, fast gelu, dot W2, reduce, sigmoid ----
  const int q = L >> 4;
  float w1l0[4], w1l1[4], bb1[4], ww2[4];
  #pragma unroll
  for (int u = 0; u < 4; ++u) {
    int n = w * 64 + u * 16 + nl;
    w1l0[u] = W1[512 * HDIM + n];
    w1l1[u] = W1[513 * HDIM + n];
    bb1[u] = b1[n];
    ww2[u] = W2[n];
  }
  #pragma unroll
  for (int s = 0; s < 4; ++s) {
    #pragma unroll
    for (int r = 0; r < 4; ++r) {
      int m = s * 16 + q * 4 + r;     // C/D: row = quad*4 + reg
      float l0v = sLab0[m], l1v = sLab1[m];
      float v = 0.f;
      #pragma unroll
      for (int u = 0; u < 4; ++u) {
        float e = acc[s][u][r] + l0v * w1l0[u] + l1v * w1l1[u] + bb1[u];
        v += gelu_fast(e) * ww2[u];
      }
      v += __shfl_xor(v, 1, 64);
      v += __shfl_xor(v, 2, 64);
      v += __shfl_xor(v, 4, 64);
      v += __shfl_xor(v, 8, 64);       // sum over 16 lanes of the quad
      if (nl == 0) sScore[m * 4 + w] = v;
    }
  }
  __syncthreads();
  if (tid < 64) {
    float s4 = sScore[tid * 4 + 0] + sScore[tid * 4 + 1] + sScore[tid * 4 + 2] +
               sScore[tid * 4 + 3] + b2[0];
    float hsv = fast_rcp(1.0f + __expf(-s4));
    int gi = i0 + (tid >> 3), gj = j0 + (tid & 7);
    out_hs[(size_t)gi * BN + gj] = hsv;
  }
}

// ---------------- row softmax of adj + TAU*log(hs + EPS) ----------------
__global__ __launch_bounds__(256) void softmax_kernel(const float* __restrict__ adj,
                                                      const float* __restrict__ hs,
                                                      float* __restrict__ out) {
  int i = blockIdx.x, t = threadIdx.x;
  __shared__ float redm[4];
  __shared__ float reds[4];
  float l[4];
  float mx = -1e30f;
  #pragma unroll
  for (int k = 0; k < 4; ++k) {
    int j = t + k * 256;
    float lv = adj[(size_t)i * BN + j] + TAUF * __logf(hs[(size_t)i * BN + j] + EPSF);
    l[k] = lv;
    mx = fmaxf(mx, lv);
  }
  #pragma unroll
  for (int o = 1; o <= 32; o <<= 1) mx = fmaxf(mx, __shfl_xor(mx, o, 64));
  if ((t & 63) == 0) redm[t >> 6] = mx;
  __syncthreads();
  mx = fmaxf(fmaxf(redm[0], redm[1]), fmaxf(redm[2], redm[3]));
  float ex[4];
  float se = 0.f;
  #pragma unroll
  for (int k = 0; k < 4; ++k) { ex[k] = __expf(l[k] - mx); se += ex[k]; }
  #pragma unroll
  for (int o = 1; o <= 32; o <<= 1) se += __shfl_xor(se, o, 64);
  if ((t & 63) == 0) reds[t >> 6] = se;
  __syncthreads();
  se = reds[0] + reds[1] + reds[2] + reds[3];
  float inv = fast_rcp(se);
  #pragma unroll
  for (int k = 0; k < 4; ++k) out[(size_t)i * BN + t + k * 256] = ex[k] * inv;
}

extern "C" void kernel_launch(void* const* d_in, const int* in_sizes, int n_in,
                              void* d_out, int out_size, void* d_ws, size_t ws_size,
                              hipStream_t stream) {
  (void)in_sizes; (void)n_in; (void)out_size; (void)ws_size;
  const float* X   = (const float*)d_in[0];
  const float* lg  = (const float*)d_in[1];
  const float* adj = (const float*)d_in[2];
  const float* W1  = (const float*)d_in[3];
  const float* b1  = (const float*)d_in[4];
  const float* W2  = (const float*)d_in[5];
  const float* b2  = (const float*)d_in[6];
  float* out = (float*)d_out;                       // [0,B^2): adj_refined, [B^2,2B^2): h_scores
  _Float16* w1h = (_Float16*)d_ws;                  // 512*256 fp16 = 256 KB
  float* oh = (float*)((char*)d_ws + FEATN * HDIM * 2);  // 1024*2 f32

  float* out_hs = out + (size_t)BN * BN;

  prep_kernel<<<dim3(FEATN + 4), dim3(256), 0, stream>>>(W1, lg, w1h, oh);
  gemm_kernel<<<dim3(128, 128), dim3(256), 0, stream>>>(X, w1h, oh, W1, b1, W2, b2, out_hs);
  softmax_kernel<<<dim3(BN), dim3(256), 0, stream>>>(adj, out_hs, out);
}